// Round 13
// baseline (432.286 us; speedup 1.0000x reference)
//
#include <hip/hip_runtime.h>
#include <math.h>

#define P 512
#define KC 10
#define NB 32
#define EPSV 0.01f
#define TR_ROWS 448
#define XT 17024   // padded columns: 16384 + per-class 64-alignment (max 17014)
#define KSPLIT 8   // gram K-split factor (R13: isolated test of 8; R7-proven at 4)

typedef __attribute__((ext_vector_type(8))) __bf16 bf16x8;
typedef __attribute__((ext_vector_type(4))) float floatx4;

// ---------------- fused histogram + padded offsets + colmap scatter (one block) ----------------
__global__ __launch_bounds__(256) void sort_k(const int* __restrict__ Y, int* __restrict__ colmap,
                                              int* __restrict__ counts, int* __restrict__ off_pad, int m){
  __shared__ int cnt[KC], offp[KC + 1], cur[KC];
  int tid = threadIdx.x;
  if (tid < KC) cnt[tid] = 0;
  __syncthreads();
  for (int i = tid; i < m; i += 256){
    int y = Y[i];
    if (y >= 0 && y < KC) atomicAdd(&cnt[y], 1);
  }
  __syncthreads();
  if (tid == 0){
    int s = 0;
    for (int j = 0; j < KC; ++j){ offp[j] = s; s += ((cnt[j] + 63) >> 6) << 6; }
    offp[KC] = s;
  }
  __syncthreads();
  if (tid < KC){ cur[tid] = offp[tid]; counts[tid] = cnt[tid]; off_pad[tid] = offp[tid]; }
  if (tid == KC) off_pad[KC] = offp[KC];
  for (int i = tid; i < XT; i += 256) colmap[i] = -1;
  __syncthreads();
  for (int i = tid; i < m; i += 256){
    int y = Y[i];
    if (y >= 0 && y < KC){
      int pos = atomicAdd(&cur[y], 1);
      colmap[pos] = i;
    }
  }
}

// ---------------- transpose + split-bf16 convert: X[m][512] -> Xt_hi/lo[512][XT] ----------------
__global__ __launch_bounds__(256) void xt_k(const float* __restrict__ X, const int* __restrict__ colmap,
                                            __bf16* __restrict__ Xhi, __bf16* __restrict__ Xlo){
  __shared__ float T[64][65];
  int c0 = blockIdx.x * 64;
  int f0 = blockIdx.y * 64;
  int tid = threadIdx.x;

  int j = tid >> 2;          // col within tile
  int piece = tid & 3;       // 16-feature piece
  int s = colmap[c0 + j];
  if (s >= 0){
    const float* src = X + (long)s * P + f0 + piece * 16;
    #pragma unroll
    for (int q = 0; q < 4; ++q){
      float4 v = *(const float4*)(src + q * 4);
      T[piece * 16 + q * 4 + 0][j] = v.x;
      T[piece * 16 + q * 4 + 1][j] = v.y;
      T[piece * 16 + q * 4 + 2][j] = v.z;
      T[piece * 16 + q * 4 + 3][j] = v.w;
    }
  } else {
    #pragma unroll
    for (int q = 0; q < 16; ++q) T[piece * 16 + q][j] = 0.f;
  }
  __syncthreads();

  int f = tid >> 2;
  int cp = (tid & 3) * 16;
  bf16x8 vh0, vl0, vh1, vl1;
  #pragma unroll
  for (int q = 0; q < 8; ++q){
    float x0 = T[f][cp + q];
    float x1 = T[f][cp + 8 + q];
    __bf16 h0 = (__bf16)x0, h1 = (__bf16)x1;
    vh0[q] = h0; vl0[q] = (__bf16)(x0 - (float)h0);
    vh1[q] = h1; vl1[q] = (__bf16)(x1 - (float)h1);
  }
  long base = (long)(f0 + f) * XT + c0 + cp;
  *(bf16x8*)&Xhi[base]     = vh0;
  *(bf16x8*)&Xhi[base + 8] = vh1;
  *(bf16x8*)&Xlo[base]     = vl0;
  *(bf16x8*)&Xlo[base + 8] = vl1;
}

// ---------------- per-class Gram via MFMA, split-bf16, K-split x8 + atomic accumulate ----------------
__global__ __launch_bounds__(256) void gram_mfma(const __bf16* __restrict__ Xhi,
                                                 const __bf16* __restrict__ Xlo,
                                                 const int* __restrict__ counts,
                                                 const int* __restrict__ off_pad,
                                                 float* __restrict__ Gk){
  int cls = blockIdx.y;
  int ta = 0, rem = blockIdx.x;
  while (rem >= ta + 1){ rem -= ta + 1; ++ta; }
  int tb = rem;
  int a0 = ta * 64, b0 = tb * 64;

  int tid  = threadIdx.x;
  int lane = tid & 63;
  int wv   = tid >> 6;
  int wrow = wv >> 1, wcol = wv & 1;
  int fr   = lane & 15;
  int quad = lane >> 4;

  int cs0     = off_pad[cls];
  int nchunks = (counts[cls] + 31) >> 5;
  int nper    = (nchunks + KSPLIT - 1) / KSPLIT;
  int ch0     = blockIdx.z * nper;
  int ch1     = min(nchunks, ch0 + nper);

  long arow0 = (long)(a0 + wrow * 32 + fr) * XT;
  long brow0 = (long)(b0 + wcol * 32 + fr) * XT;

  floatx4 acc[2][2];
  #pragma unroll
  for (int i = 0; i < 2; ++i)
    #pragma unroll
    for (int j = 0; j < 2; ++j) acc[i][j] = (floatx4){0.f, 0.f, 0.f, 0.f};

#define GLOAD(AH, AL, BH, BL, CH)                                            \
  { long co = cs0 + (long)(CH) * 32 + quad * 8;                              \
    for (int r = 0; r < 2; ++r){                                             \
      AH[r] = *(const bf16x8*)&Xhi[arow0 + (long)r * 16 * XT + co];          \
      AL[r] = *(const bf16x8*)&Xlo[arow0 + (long)r * 16 * XT + co];          \
      BH[r] = *(const bf16x8*)&Xhi[brow0 + (long)r * 16 * XT + co];          \
      BL[r] = *(const bf16x8*)&Xlo[brow0 + (long)r * 16 * XT + co]; } }

  if (ch0 < ch1){
    bf16x8 ah[2], al[2], bh[2], bl[2];
    GLOAD(ah, al, bh, bl, ch0)
    for (int ch = ch0; ch < ch1; ++ch){
      bf16x8 nh[2], nl[2], mh[2], ml[2];
      if (ch + 1 < ch1) GLOAD(nh, nl, mh, ml, ch + 1)
      #pragma unroll
      for (int ri = 0; ri < 2; ++ri)
        #pragma unroll
        for (int rj = 0; rj < 2; ++rj){
          acc[ri][rj] = __builtin_amdgcn_mfma_f32_16x16x32_bf16(al[ri], bh[rj], acc[ri][rj], 0, 0, 0);
          acc[ri][rj] = __builtin_amdgcn_mfma_f32_16x16x32_bf16(ah[ri], bl[rj], acc[ri][rj], 0, 0, 0);
          acc[ri][rj] = __builtin_amdgcn_mfma_f32_16x16x32_bf16(ah[ri], bh[rj], acc[ri][rj], 0, 0, 0);
        }
      if (ch + 1 < ch1){
        #pragma unroll
        for (int r = 0; r < 2; ++r){ ah[r] = nh[r]; al[r] = nl[r]; bh[r] = mh[r]; bl[r] = ml[r]; }
      }
    }
  }
#undef GLOAD

  float* C = Gk + (long)cls * P * P;
  #pragma unroll
  for (int ri = 0; ri < 2; ++ri){
    int a = a0 + wrow * 32 + ri * 16 + (lane >> 4) * 4;
    #pragma unroll
    for (int rj = 0; rj < 2; ++rj){
      int b = b0 + wcol * 32 + rj * 16 + (lane & 15);
      #pragma unroll
      for (int r = 0; r < 4; ++r)
        atomicAdd(&C[(long)(a + r) * P + b], acc[ri][rj][r]);
    }
  }
}

// ---------------- slot 10 = sum of class Grams ----------------
__global__ __launch_bounds__(256) void sum10_k(float* __restrict__ Gk){
  long i = (long)blockIdx.x * 256 + threadIdx.x;
  float4 s = {0.f, 0.f, 0.f, 0.f};
  #pragma unroll
  for (int j = 0; j < KC; ++j){
    float4 v = ((const float4*)(Gk + (long)j * P * P))[i];
    s.x += v.x; s.y += v.y; s.z += v.z; s.w += v.w;
  }
  ((float4*)(Gk + (long)KC * P * P))[i] = s;
}

// ---------------- single-block-per-matrix MFMA Cholesky logdet (R7-exact, 234 us) ----------------
// Session constraint (R4/R8/R12 evidence): only strictly barrier-separated phases are
// safe on this codebase; all overlap variants NaN'd. This is the proven floor config:
// 512 thr / 92 VGPR / 3 barriers per step.
__global__ __launch_bounds__(512, 2) void chol_mfma(float* __restrict__ Gk,
                                                    const int* __restrict__ counts,
                                                    float* __restrict__ logdets,
                                                    float m_tot){
  __shared__ __bf16 Lhi[TR_ROWS * 32];
  __shared__ __bf16 Llo[TR_ROWS * 32];
  __shared__ float  Ld[NB * 33];
  __shared__ float  Ldr[NB];

  int mat  = blockIdx.x;
  int tid  = threadIdx.x;
  int lane = tid & 63;
  int wv   = tid >> 6;                       // 0..7
  float* A = Gk + (long)mat * P * P;
  float sc = (mat < KC) ? ((float)P / (((float)counts[mat] + 1e-8f) * EPSV))
                        : ((float)P / (m_tot * EPSV));
  float logsum = 0.f;                        // accumulated in log2

  for (int s = 0; s < 16; ++s){
    int j0 = s * NB;
    int qt = P - j0 - NB;

    if (wv == 0){
      float a[NB];
      if (lane < NB){
        const float* src = A + (long)(j0 + lane) * P + j0;
        #pragma unroll
        for (int u = 0; u < NB; u += 4){
          float4 v = *(const float4*)(src + u);
          a[u] = v.x; a[u+1] = v.y; a[u+2] = v.z; a[u+3] = v.w;
        }
        if (s == 0){
          #pragma unroll
          for (int u = 0; u < NB; ++u) a[u] *= sc;
          a[lane] += 1.0f;
        }
      } else {
        #pragma unroll
        for (int u = 0; u < NB; ++u) a[u] = 0.f;
      }
      #pragma unroll
      for (int jj = 0; jj < NB; ++jj){
        float d = __shfl(a[jj], jj);
        logsum += __log2f(d);                // wave-uniform
        float inv = 1.0f / d;
        float rs  = rsqrtf(d);
        float w   = a[jj] * inv;
        #pragma unroll
        for (int l = 0; l < NB; ++l){
          if (l > jj){
            float prl = __shfl(a[l], jj);
            a[l] -= w * prl;
          }
        }
        a[jj] *= rs;
      }
      if (lane < NB){
        #pragma unroll
        for (int u = 0; u < NB; ++u) Ld[lane * 33 + u] = a[u];
        Ldr[lane] = 1.0f / a[lane];
      }
    }
    __syncthreads();

    if (qt > 0){
      if (tid < qt){
        float b[NB];
        const float* src = A + (long)(j0 + NB + tid) * P + j0;
        #pragma unroll
        for (int u = 0; u < NB; u += 4){
          float4 v = *(const float4*)(src + u);
          b[u] = v.x; b[u+1] = v.y; b[u+2] = v.z; b[u+3] = v.w;
        }
        if (s == 0){
          #pragma unroll
          for (int u = 0; u < NB; ++u) b[u] *= sc;
        }
        #pragma unroll
        for (int jj = 0; jj < NB; ++jj){
          float acc = b[jj];
          for (int u = 0; u < jj; ++u) acc -= b[u] * Ld[jj * 33 + u];
          b[jj] = acc * Ldr[jj];
        }
        int t = tid;
        #pragma unroll
        for (int c = 0; c < 4; ++c){
          int sw = (t * 4 + (c ^ ((t >> 1) & 3))) * 8;
          bf16x8 vh, vl;
          #pragma unroll
          for (int j = 0; j < 8; ++j){
            float f = b[c * 8 + j];
            __bf16 h = (__bf16)f;
            vh[j] = h;
            vl[j] = (__bf16)(f - (float)h);
          }
          *(bf16x8*)&Lhi[sw] = vh;
          *(bf16x8*)&Llo[sw] = vl;
        }
      }
    }
    __syncthreads();

    if (qt > 0){
      int tt = qt >> 5;
      int T  = tt * (tt + 1) / 2;
      int trail0 = j0 + NB;
      for (int idx = wv; idx < T; idx += 8){
        int ti = 0, rem = idx;
        while (rem >= ti + 1){ rem -= ti + 1; ++ti; }
        int tj = rem;
        int I0 = ti * 32, J0 = tj * 32;
        int c  = lane >> 4;

        bf16x8 ahi[2], alo[2], bhi[2], blo[2];
        #pragma unroll
        for (int h = 0; h < 2; ++h){
          int r1 = I0 + h * 16 + (lane & 15);
          int sw1 = (r1 * 4 + (c ^ ((r1 >> 1) & 3))) * 8;
          ahi[h] = *(const bf16x8*)&Lhi[sw1];
          alo[h] = *(const bf16x8*)&Llo[sw1];
          int r2 = J0 + h * 16 + (lane & 15);
          int sw2 = (r2 * 4 + (c ^ ((r2 >> 1) & 3))) * 8;
          bhi[h] = *(const bf16x8*)&Lhi[sw2];
          blo[h] = *(const bf16x8*)&Llo[sw2];
        }

        #pragma unroll
        for (int hi_ = 0; hi_ < 2; ++hi_){
          #pragma unroll
          for (int hj = 0; hj < 2; ++hj){
            floatx4 acc = {0.f, 0.f, 0.f, 0.f};
            acc = __builtin_amdgcn_mfma_f32_16x16x32_bf16(alo[hi_], bhi[hj], acc, 0, 0, 0);
            acc = __builtin_amdgcn_mfma_f32_16x16x32_bf16(ahi[hi_], blo[hj], acc, 0, 0, 0);
            acc = __builtin_amdgcn_mfma_f32_16x16x32_bf16(ahi[hi_], bhi[hj], acc, 0, 0, 0);
            int grow0 = trail0 + I0 + hi_ * 16 + (lane >> 4) * 4;
            int gcol  = trail0 + J0 + hj  * 16 + (lane & 15);
            #pragma unroll
            for (int r = 0; r < 4; ++r){
              long off = (long)(grow0 + r) * P + gcol;
              float v = A[off];
              if (s == 0) v = sc * v + ((grow0 + r) == gcol ? 1.f : 0.f);
              A[off] = v - acc[r];
            }
          }
        }
      }
    }
    __syncthreads();
  }

  if (tid == 0) logdets[mat] = logsum * 0.6931471805599453f;   // log2 -> ln
}

// ---------------- final reduction ----------------
__global__ __launch_bounds__(64) void final_k(const float* __restrict__ logdets,
                                              const int* __restrict__ counts,
                                              float* __restrict__ out, float m_tot){
  if (threadIdx.x == 0 && blockIdx.x == 0){
    out[0] = 0.5f * logdets[KC];
    float comp = 0.f;
    for (int j = 0; j < KC; ++j){
      float trPi = (float)counts[j] + 1e-8f;
      comp += logdets[j] * trPi / m_tot;
    }
    out[1] = 0.5f * comp;
  }
}

extern "C" void kernel_launch(void* const* d_in, const int* in_sizes, int n_in,
                              void* d_out, int out_size, void* d_ws, size_t ws_size,
                              hipStream_t stream) {
  (void)n_in; (void)out_size; (void)ws_size;
  const float* X = (const float*)d_in[0];
  const int*   Y = (const int*)d_in[1];
  int m = in_sizes[0] / P;     // 16384

  float*  Gk      = (float*)d_ws;                    // 11 * P*P floats (11 MB)
  __bf16* Xhi     = (__bf16*)(Gk + 11L * P * P);     // 512*XT bf16 (17.4 MB)
  __bf16* Xlo     = Xhi + (long)P * XT;              // 512*XT bf16
  int*    colmap  = (int*)(Xlo + (long)P * XT);      // XT ints
  int*    counts  = colmap + XT;                     // 16
  int*    off_pad = counts + 16;                     // 17
  float*  logdets = (float*)(off_pad + 17);          // 16

  sort_k<<<1, 256, 0, stream>>>(Y, colmap, counts, off_pad, m);

  dim3 xg(XT / 64, 8);
  xt_k<<<xg, 256, 0, stream>>>(X, colmap, Xhi, Xlo);

  // zero class Grams (gram_mfma accumulates atomically across K-splits)
  hipMemsetAsync(Gk, 0, (size_t)KC * P * P * sizeof(float), stream);

  dim3 gg(36, KC, KSPLIT);
  gram_mfma<<<gg, 256, 0, stream>>>(Xhi, Xlo, counts, off_pad, Gk);

  sum10_k<<<P * P / 1024, 256, 0, stream>>>(Gk);

  chol_mfma<<<KC + 1, 512, 0, stream>>>(Gk, counts, logdets, (float)m);

  final_k<<<1, 64, 0, stream>>>(logdets, counts, (float*)d_out, (float)m);
}

// Round 17
// 419.291 us; speedup vs baseline: 1.0310x; 1.0310x over previous
//
#include <hip/hip_runtime.h>
#include <math.h>

#define P 512
#define KC 10
#define NB 32
#define EPSV 0.01f
#define TR_ROWS 448
#define XT 17024   // padded columns: 16384 + per-class 64-alignment (max 17014)
#define KSPLIT 8   // gram K-split factor
#define LDS_T 36   // Ld row stride (floats): 144B rows -> 16B-aligned float4 reads

typedef __attribute__((ext_vector_type(8))) __bf16 bf16x8;
typedef __attribute__((ext_vector_type(4))) float floatx4;

// ---------------- fused histogram + padded offsets + colmap scatter (one block) ----------------
__global__ __launch_bounds__(256) void sort_k(const int* __restrict__ Y, int* __restrict__ colmap,
                                              int* __restrict__ counts, int* __restrict__ off_pad, int m){
  __shared__ int cnt[KC], offp[KC + 1], cur[KC];
  int tid = threadIdx.x;
  if (tid < KC) cnt[tid] = 0;
  __syncthreads();
  for (int i = tid; i < m; i += 256){
    int y = Y[i];
    if (y >= 0 && y < KC) atomicAdd(&cnt[y], 1);
  }
  __syncthreads();
  if (tid == 0){
    int s = 0;
    for (int j = 0; j < KC; ++j){ offp[j] = s; s += ((cnt[j] + 63) >> 6) << 6; }
    offp[KC] = s;
  }
  __syncthreads();
  if (tid < KC){ cur[tid] = offp[tid]; counts[tid] = cnt[tid]; off_pad[tid] = offp[tid]; }
  if (tid == KC) off_pad[KC] = offp[KC];
  for (int i = tid; i < XT; i += 256) colmap[i] = -1;
  __syncthreads();
  for (int i = tid; i < m; i += 256){
    int y = Y[i];
    if (y >= 0 && y < KC){
      int pos = atomicAdd(&cur[y], 1);
      colmap[pos] = i;
    }
  }
}

// ---------------- transpose + split-bf16 convert: X[m][512] -> Xt_hi/lo[512][XT] ----------------
__global__ __launch_bounds__(256) void xt_k(const float* __restrict__ X, const int* __restrict__ colmap,
                                            __bf16* __restrict__ Xhi, __bf16* __restrict__ Xlo){
  __shared__ float T[64][65];
  int c0 = blockIdx.x * 64;
  int f0 = blockIdx.y * 64;
  int tid = threadIdx.x;

  int j = tid >> 2;          // col within tile
  int piece = tid & 3;       // 16-feature piece
  int s = colmap[c0 + j];
  if (s >= 0){
    const float* src = X + (long)s * P + f0 + piece * 16;
    #pragma unroll
    for (int q = 0; q < 4; ++q){
      float4 v = *(const float4*)(src + q * 4);
      T[piece * 16 + q * 4 + 0][j] = v.x;
      T[piece * 16 + q * 4 + 1][j] = v.y;
      T[piece * 16 + q * 4 + 2][j] = v.z;
      T[piece * 16 + q * 4 + 3][j] = v.w;
    }
  } else {
    #pragma unroll
    for (int q = 0; q < 16; ++q) T[piece * 16 + q][j] = 0.f;
  }
  __syncthreads();

  int f = tid >> 2;
  int cp = (tid & 3) * 16;
  bf16x8 vh0, vl0, vh1, vl1;
  #pragma unroll
  for (int q = 0; q < 8; ++q){
    float x0 = T[f][cp + q];
    float x1 = T[f][cp + 8 + q];
    __bf16 h0 = (__bf16)x0, h1 = (__bf16)x1;
    vh0[q] = h0; vl0[q] = (__bf16)(x0 - (float)h0);
    vh1[q] = h1; vl1[q] = (__bf16)(x1 - (float)h1);
  }
  long base = (long)(f0 + f) * XT + c0 + cp;
  *(bf16x8*)&Xhi[base]     = vh0;
  *(bf16x8*)&Xhi[base + 8] = vh1;
  *(bf16x8*)&Xlo[base]     = vl0;
  *(bf16x8*)&Xlo[base + 8] = vl1;
}

// ---------------- per-class Gram via MFMA, split-bf16, K-split x8 + atomic accumulate ----------------
__global__ __launch_bounds__(256) void gram_mfma(const __bf16* __restrict__ Xhi,
                                                 const __bf16* __restrict__ Xlo,
                                                 const int* __restrict__ counts,
                                                 const int* __restrict__ off_pad,
                                                 float* __restrict__ Gk){
  int cls = blockIdx.y;
  int ta = 0, rem = blockIdx.x;
  while (rem >= ta + 1){ rem -= ta + 1; ++ta; }
  int tb = rem;
  int a0 = ta * 64, b0 = tb * 64;

  int tid  = threadIdx.x;
  int lane = tid & 63;
  int wv   = tid >> 6;
  int wrow = wv >> 1, wcol = wv & 1;
  int fr   = lane & 15;
  int quad = lane >> 4;

  int cs0     = off_pad[cls];
  int nchunks = (counts[cls] + 31) >> 5;
  int nper    = (nchunks + KSPLIT - 1) / KSPLIT;
  int ch0     = blockIdx.z * nper;
  int ch1     = min(nchunks, ch0 + nper);

  long arow0 = (long)(a0 + wrow * 32 + fr) * XT;
  long brow0 = (long)(b0 + wcol * 32 + fr) * XT;

  floatx4 acc[2][2];
  #pragma unroll
  for (int i = 0; i < 2; ++i)
    #pragma unroll
    for (int j = 0; j < 2; ++j) acc[i][j] = (floatx4){0.f, 0.f, 0.f, 0.f};

#define GLOAD(AH, AL, BH, BL, CH)                                            \
  { long co = cs0 + (long)(CH) * 32 + quad * 8;                              \
    for (int r = 0; r < 2; ++r){                                             \
      AH[r] = *(const bf16x8*)&Xhi[arow0 + (long)r * 16 * XT + co];          \
      AL[r] = *(const bf16x8*)&Xlo[arow0 + (long)r * 16 * XT + co];          \
      BH[r] = *(const bf16x8*)&Xhi[brow0 + (long)r * 16 * XT + co];          \
      BL[r] = *(const bf16x8*)&Xlo[brow0 + (long)r * 16 * XT + co]; } }

  if (ch0 < ch1){
    bf16x8 ah[2], al[2], bh[2], bl[2];
    GLOAD(ah, al, bh, bl, ch0)
    for (int ch = ch0; ch < ch1; ++ch){
      bf16x8 nh[2], nl[2], mh[2], ml[2];
      if (ch + 1 < ch1) GLOAD(nh, nl, mh, ml, ch + 1)
      #pragma unroll
      for (int ri = 0; ri < 2; ++ri)
        #pragma unroll
        for (int rj = 0; rj < 2; ++rj){
          acc[ri][rj] = __builtin_amdgcn_mfma_f32_16x16x32_bf16(al[ri], bh[rj], acc[ri][rj], 0, 0, 0);
          acc[ri][rj] = __builtin_amdgcn_mfma_f32_16x16x32_bf16(ah[ri], bl[rj], acc[ri][rj], 0, 0, 0);
          acc[ri][rj] = __builtin_amdgcn_mfma_f32_16x16x32_bf16(ah[ri], bh[rj], acc[ri][rj], 0, 0, 0);
        }
      if (ch + 1 < ch1){
        #pragma unroll
        for (int r = 0; r < 2; ++r){ ah[r] = nh[r]; al[r] = nl[r]; bh[r] = mh[r]; bl[r] = ml[r]; }
      }
    }
  }
#undef GLOAD

  float* C = Gk + (long)cls * P * P;
  #pragma unroll
  for (int ri = 0; ri < 2; ++ri){
    int a = a0 + wrow * 32 + ri * 16 + (lane >> 4) * 4;
    #pragma unroll
    for (int rj = 0; rj < 2; ++rj){
      int b = b0 + wcol * 32 + rj * 16 + (lane & 15);
      #pragma unroll
      for (int r = 0; r < 4; ++r)
        atomicAdd(&C[(long)(a + r) * P + b], acc[ri][rj][r]);
    }
  }
}

// ---------------- slot 10 = sum of class Grams ----------------
__global__ __launch_bounds__(256) void sum10_k(float* __restrict__ Gk){
  long i = (long)blockIdx.x * 256 + threadIdx.x;
  float4 s = {0.f, 0.f, 0.f, 0.f};
  #pragma unroll
  for (int j = 0; j < KC; ++j){
    float4 v = ((const float4*)(Gk + (long)j * P * P))[i];
    s.x += v.x; s.y += v.y; s.z += v.z; s.w += v.w;
  }
  ((float4*)(Gk + (long)KC * P * P))[i] = s;
}

// ---------------- single-block-per-matrix MFMA Cholesky logdet ----------------
// R17: R13-exact structure (3 barriers/step, no overlap, no readlane). ONE change:
// Ld panel stride 33 -> 36 (rows 144B = 16B-aligned) + phase-2 inner loop reads
// L-rows as explicit float4 (136 ds_read_b128 broadcasts replace 496 ds_read_b32;
// with stride 33 rows were only 4B-aligned so the compiler could NOT merge them).
// Phase 2 was ~23k cy/step on the single LDS pipe = ~65% of chol by the cycle model.
__global__ __launch_bounds__(512, 2) void chol_mfma(float* __restrict__ Gk,
                                                    const int* __restrict__ counts,
                                                    float* __restrict__ logdets,
                                                    float m_tot){
  __shared__ __bf16 Lhi[TR_ROWS * 32];
  __shared__ __bf16 Llo[TR_ROWS * 32];
  __shared__ __align__(16) float Ld[NB * LDS_T];
  __shared__ float Ldr[NB];

  int mat  = blockIdx.x;
  int tid  = threadIdx.x;
  int lane = tid & 63;
  int wv   = tid >> 6;                       // 0..7
  float* A = Gk + (long)mat * P * P;
  float sc = (mat < KC) ? ((float)P / (((float)counts[mat] + 1e-8f) * EPSV))
                        : ((float)P / (m_tot * EPSV));
  float logsum = 0.f;                        // accumulated in log2

  for (int s = 0; s < 16; ++s){
    int j0 = s * NB;
    int qt = P - j0 - NB;

    // ---- phase 1: 32x32 panel Cholesky, wave 0 (R1-exact __shfl version) ----
    if (wv == 0){
      float a[NB];
      if (lane < NB){
        const float* src = A + (long)(j0 + lane) * P + j0;
        #pragma unroll
        for (int u = 0; u < NB; u += 4){
          float4 v = *(const float4*)(src + u);
          a[u] = v.x; a[u+1] = v.y; a[u+2] = v.z; a[u+3] = v.w;
        }
        if (s == 0){
          #pragma unroll
          for (int u = 0; u < NB; ++u) a[u] *= sc;
          a[lane] += 1.0f;
        }
      } else {
        #pragma unroll
        for (int u = 0; u < NB; ++u) a[u] = 0.f;
      }
      #pragma unroll
      for (int jj = 0; jj < NB; ++jj){
        float d = __shfl(a[jj], jj);
        logsum += __log2f(d);                // wave-uniform
        float inv = 1.0f / d;
        float rs  = rsqrtf(d);
        float w   = a[jj] * inv;
        #pragma unroll
        for (int l = 0; l < NB; ++l){
          if (l > jj){
            float prl = __shfl(a[l], jj);
            a[l] -= w * prl;
          }
        }
        a[jj] *= rs;
      }
      if (lane < NB){
        #pragma unroll
        for (int u = 0; u < NB; ++u) Ld[lane * LDS_T + u] = a[u];
        Ldr[lane] = 1.0f / a[lane];
      }
    }
    __syncthreads();

    // ---- phase 2: forward substitution; L-rows read as float4 broadcasts ----
    if (qt > 0){
      if (tid < qt){
        float b[NB];
        const float* src = A + (long)(j0 + NB + tid) * P + j0;
        #pragma unroll
        for (int u = 0; u < NB; u += 4){
          float4 v = *(const float4*)(src + u);
          b[u] = v.x; b[u+1] = v.y; b[u+2] = v.z; b[u+3] = v.w;
        }
        if (s == 0){
          #pragma unroll
          for (int u = 0; u < NB; ++u) b[u] *= sc;
        }
        #pragma unroll
        for (int jj = 0; jj < NB; ++jj){
          float acc = b[jj];
          #pragma unroll
          for (int c0 = 0; c0 < jj; c0 += 4){                  // bounds compile-time after unroll
            float4 lr = *(const float4*)&Ld[jj * LDS_T + c0];  // 16B-aligned broadcast
            acc = fmaf(-b[c0], lr.x, acc);
            if (c0 + 1 < jj) acc = fmaf(-b[c0 + 1], lr.y, acc);
            if (c0 + 2 < jj) acc = fmaf(-b[c0 + 2], lr.z, acc);
            if (c0 + 3 < jj) acc = fmaf(-b[c0 + 3], lr.w, acc);
          }
          b[jj] = acc * Ldr[jj];
        }
        int t = tid;
        #pragma unroll
        for (int c = 0; c < 4; ++c){
          int sw = (t * 4 + (c ^ ((t >> 1) & 3))) * 8;
          bf16x8 vh, vl;
          #pragma unroll
          for (int j = 0; j < 8; ++j){
            float f = b[c * 8 + j];
            __bf16 h = (__bf16)f;
            vh[j] = h;
            vl[j] = (__bf16)(f - (float)h);
          }
          *(bf16x8*)&Lhi[sw] = vh;
          *(bf16x8*)&Llo[sw] = vl;
        }
      }
    }
    __syncthreads();

    // ---- phase 3: trailing update A22 -= L21 L21^T (unchanged) ----
    if (qt > 0){
      int tt = qt >> 5;
      int T  = tt * (tt + 1) / 2;
      int trail0 = j0 + NB;
      for (int idx = wv; idx < T; idx += 8){
        int ti = 0, rem = idx;
        while (rem >= ti + 1){ rem -= ti + 1; ++ti; }
        int tj = rem;
        int I0 = ti * 32, J0 = tj * 32;
        int c  = lane >> 4;

        bf16x8 ahi[2], alo[2], bhi[2], blo[2];
        #pragma unroll
        for (int h = 0; h < 2; ++h){
          int r1 = I0 + h * 16 + (lane & 15);
          int sw1 = (r1 * 4 + (c ^ ((r1 >> 1) & 3))) * 8;
          ahi[h] = *(const bf16x8*)&Lhi[sw1];
          alo[h] = *(const bf16x8*)&Llo[sw1];
          int r2 = J0 + h * 16 + (lane & 15);
          int sw2 = (r2 * 4 + (c ^ ((r2 >> 1) & 3))) * 8;
          bhi[h] = *(const bf16x8*)&Lhi[sw2];
          blo[h] = *(const bf16x8*)&Llo[sw2];
        }

        #pragma unroll
        for (int hi_ = 0; hi_ < 2; ++hi_){
          #pragma unroll
          for (int hj = 0; hj < 2; ++hj){
            floatx4 acc = {0.f, 0.f, 0.f, 0.f};
            acc = __builtin_amdgcn_mfma_f32_16x16x32_bf16(alo[hi_], bhi[hj], acc, 0, 0, 0);
            acc = __builtin_amdgcn_mfma_f32_16x16x32_bf16(ahi[hi_], blo[hj], acc, 0, 0, 0);
            acc = __builtin_amdgcn_mfma_f32_16x16x32_bf16(ahi[hi_], bhi[hj], acc, 0, 0, 0);
            int grow0 = trail0 + I0 + hi_ * 16 + (lane >> 4) * 4;
            int gcol  = trail0 + J0 + hj  * 16 + (lane & 15);
            #pragma unroll
            for (int r = 0; r < 4; ++r){
              long off = (long)(grow0 + r) * P + gcol;
              float v = A[off];
              if (s == 0) v = sc * v + ((grow0 + r) == gcol ? 1.f : 0.f);
              A[off] = v - acc[r];
            }
          }
        }
      }
    }
    __syncthreads();
  }

  if (tid == 0) logdets[mat] = logsum * 0.6931471805599453f;   // log2 -> ln
}

// ---------------- final reduction ----------------
__global__ __launch_bounds__(64) void final_k(const float* __restrict__ logdets,
                                              const int* __restrict__ counts,
                                              float* __restrict__ out, float m_tot){
  if (threadIdx.x == 0 && blockIdx.x == 0){
    out[0] = 0.5f * logdets[KC];
    float comp = 0.f;
    for (int j = 0; j < KC; ++j){
      float trPi = (float)counts[j] + 1e-8f;
      comp += logdets[j] * trPi / m_tot;
    }
    out[1] = 0.5f * comp;
  }
}

extern "C" void kernel_launch(void* const* d_in, const int* in_sizes, int n_in,
                              void* d_out, int out_size, void* d_ws, size_t ws_size,
                              hipStream_t stream) {
  (void)n_in; (void)out_size; (void)ws_size;
  const float* X = (const float*)d_in[0];
  const int*   Y = (const int*)d_in[1];
  int m = in_sizes[0] / P;     // 16384

  float*  Gk      = (float*)d_ws;                    // 11 * P*P floats (11 MB)
  __bf16* Xhi     = (__bf16*)(Gk + 11L * P * P);     // 512*XT bf16 (17.4 MB)
  __bf16* Xlo     = Xhi + (long)P * XT;              // 512*XT bf16
  int*    colmap  = (int*)(Xlo + (long)P * XT);      // XT ints
  int*    counts  = colmap + XT;                     // 16
  int*    off_pad = counts + 16;                     // 17
  float*  logdets = (float*)(off_pad + 17);          // 16

  sort_k<<<1, 256, 0, stream>>>(Y, colmap, counts, off_pad, m);

  dim3 xg(XT / 64, 8);
  xt_k<<<xg, 256, 0, stream>>>(X, colmap, Xhi, Xlo);

  // zero class Grams (gram_mfma accumulates atomically across K-splits)
  hipMemsetAsync(Gk, 0, (size_t)KC * P * P * sizeof(float), stream);

  dim3 gg(36, KC, KSPLIT);
  gram_mfma<<<gg, 256, 0, stream>>>(Xhi, Xlo, counts, off_pad, Gk);

  sum10_k<<<P * P / 1024, 256, 0, stream>>>(Gk);

  chol_mfma<<<KC + 1, 512, 0, stream>>>(Gk, counts, logdets, (float)m);

  final_k<<<1, 64, 0, stream>>>(logdets, counts, (float*)d_out, (float)m);
}